// Round 1
// baseline (1818.950 us; speedup 1.0000x reference)
//
#include <hip/hip_runtime.h>
#include <hip/hip_bf16.h>

#define N_NODES 10000
#define N_EDGES 100000
#define F_NODE 128
#define HEADS 8
#define OUT_CH 128
#define HC 1024

__device__ __forceinline__ void atomAddF(float* p, float v) {
    unsafeAtomicAdd(p, v);   // hardware global_atomic_add_f32 (no CAS loop)
}

// ---------------- GEMM: C[M,N] = A[M,K] @ B[K,N] + bias[N] ----------------
#define GBM 64
#define GBN 64
#define GBK 32
__global__ __launch_bounds__(256) void gemm_bias_kernel(
    const float* __restrict__ A, const float* __restrict__ B,
    const float* __restrict__ bias, float* __restrict__ C,
    int M, int N, int K) {
    __shared__ float As[GBK][GBM + 1];  // transposed A tile
    __shared__ float Bs[GBK][GBN];
    int tid = threadIdx.x;
    int n0 = blockIdx.x * GBN;
    int m0 = blockIdx.y * GBM;
    int tm = (tid >> 4) * 4;
    int tn = (tid & 15) * 4;
    float acc[4][4] = {};
    for (int k0 = 0; k0 < K; k0 += GBK) {
        // A tile 64x32: 512 float4, 2 per thread
        #pragma unroll
        for (int t = 0; t < 2; ++t) {
            int f4 = tid + t * 256;
            int r = f4 >> 3;               // 8 float4 per row of 32
            int c4 = (f4 & 7) << 2;
            float4 av = make_float4(0.f, 0.f, 0.f, 0.f);
            int gr = m0 + r;
            if (gr < M) av = *(const float4*)(A + (size_t)gr * K + k0 + c4);
            As[c4 + 0][r] = av.x; As[c4 + 1][r] = av.y;
            As[c4 + 2][r] = av.z; As[c4 + 3][r] = av.w;
        }
        // B tile 32x64: 512 float4
        #pragma unroll
        for (int t = 0; t < 2; ++t) {
            int f4 = tid + t * 256;
            int r = f4 >> 4;               // 16 float4 per row of 64
            int c4 = (f4 & 15) << 2;
            *(float4*)(&Bs[r][c4]) = *(const float4*)(B + (size_t)(k0 + r) * N + n0 + c4);
        }
        __syncthreads();
        #pragma unroll
        for (int kk = 0; kk < GBK; ++kk) {
            float a[4], b[4];
            #pragma unroll
            for (int i = 0; i < 4; ++i) a[i] = As[kk][tm + i];
            #pragma unroll
            for (int j = 0; j < 4; ++j) b[j] = Bs[kk][tn + j];
            #pragma unroll
            for (int i = 0; i < 4; ++i)
                #pragma unroll
                for (int j = 0; j < 4; ++j)
                    acc[i][j] += a[i] * b[j];
        }
        __syncthreads();
    }
    #pragma unroll
    for (int i = 0; i < 4; ++i) {
        int gr = m0 + tm + i;
        if (gr < M) {
            #pragma unroll
            for (int j = 0; j < 4; ++j)
                C[(size_t)gr * N + n0 + tn + j] = acc[i][j] + bias[n0 + tn + j];
        }
    }
}

// ---------------- qWe[n, h*16+f] = sum_c q[n,h*128+c] * We[f*1024 + h*128 + c]
__global__ __launch_bounds__(128) void qwe_kernel(
    const float* __restrict__ q, const float* __restrict__ We,
    float* __restrict__ qWe) {
    __shared__ float qrow[HC];
    int n = blockIdx.x;
    int t = threadIdx.x;  // 128
    #pragma unroll
    for (int i = 0; i < 8; ++i) qrow[t + 128 * i] = q[(size_t)n * HC + t + 128 * i];
    __syncthreads();
    int h = t >> 4, f = t & 15;
    const float* wp = We + (size_t)f * HC + h * 128;
    const float* qp = qrow + h * 128;
    float s = 0.f;
    #pragma unroll
    for (int c = 0; c < 128; ++c) s += qp[c] * wp[c];
    qWe[(size_t)n * 128 + t] = s;  // t == h*16+f
}

// ---------------- fused edge pass: one wave per edge ----------------
__global__ __launch_bounds__(256) void edge_kernel(
    const float* __restrict__ q, const float* __restrict__ k,
    const float* __restrict__ v, const float* __restrict__ qWe,
    const float* __restrict__ ea, const int* __restrict__ ei,
    float* __restrict__ s_out, float* __restrict__ t_out,
    float* __restrict__ vagg) {
    __shared__ float a_sh[4][8];
    int tid = threadIdx.x;
    int w = tid >> 6, lane = tid & 63;
    int e = blockIdx.x * 4 + w;
    if (e >= N_EDGES) return;
    int src = ei[e], dst = ei[N_EDGES + e];

    float eav = (lane < 16) ? ea[(size_t)e * 16 + lane] : 0.f;

    // edge term per head: et[h] = sum_f ea[f]*qWe[dst,h*16+f]
    // M2 mapping: lane l holds flat {2l, 2l+1}; h = l>>3, f = 2*(l&7){,+1}
    float2 qw = *(const float2*)(qWe + (size_t)dst * 128 + 2 * lane);
    int f1 = 2 * (lane & 7);
    float et = qw.x * __shfl(eav, f1) + qw.y * __shfl(eav, f1 + 1);
    et += __shfl_xor(et, 1); et += __shfl_xor(et, 2); et += __shfl_xor(et, 4);
    // now lane h*8 .. h*8+7 all hold et[h]

    const float4* q4p = (const float4*)(q + (size_t)dst * HC);
    const float4* k4p = (const float4*)(k + (size_t)src * HC);
    const float4* v4p = (const float4*)(v + (size_t)src * HC);

    // M1 mapping: chunk j, lane l -> float4 at flat 256*j + 4*l, head = 2j + (l>=32)
    float aj[4];
    #pragma unroll
    for (int j = 0; j < 4; ++j) {
        int idx = j * 64 + lane;
        float4 q4 = q4p[idx], k4 = k4p[idx];
        float d = q4.x * k4.x + q4.y * k4.y + q4.z * k4.z + q4.w * k4.w;
        d += __shfl_xor(d, 1);  d += __shfl_xor(d, 2);  d += __shfl_xor(d, 4);
        d += __shfl_xor(d, 8);  d += __shfl_xor(d, 16);
        int h = 2 * j + (lane >> 5);
        float eth = __shfl(et, h << 3);
        float a = __expf((d + eth) * 0.08838834764831845f);  // 1/sqrt(128)
        aj[j] = a;
        if ((lane & 31) == 0) a_sh[w][h] = a;
    }
    // s accumulation (one atomic per head)
    if (lane < 8) atomAddF(&s_out[(size_t)dst * 8 + lane], a_sh[w][lane]);
    // t accumulation: t[dst, h*16+f] += a[h]*ea[f]; lane covers flat {2l,2l+1}
    {
        int h = lane >> 3;
        float av = a_sh[w][h];
        float e1 = __shfl(eav, f1), e2 = __shfl(eav, f1 + 1);
        atomAddF(&t_out[(size_t)dst * 128 + 2 * lane], av * e1);
        atomAddF(&t_out[(size_t)dst * 128 + 2 * lane + 1], av * e2);
    }
    // vagg[dst, :] += a[head(flat)] * v[src, :]
    float* vo = vagg + (size_t)dst * HC;
    #pragma unroll
    for (int j = 0; j < 4; ++j) {
        int idx = j * 64 + lane;
        float4 v4 = v4p[idx];
        float a = aj[j];
        atomAddF(vo + 4 * idx + 0, a * v4.x);
        atomAddF(vo + 4 * idx + 1, a * v4.y);
        atomAddF(vo + 4 * idx + 2, a * v4.z);
        atomAddF(vo + 4 * idx + 3, a * v4.w);
    }
}

// ---------------- node epilogue: normalize, head-mean, +skip, relu, pool ---
__global__ __launch_bounds__(128) void node_epilogue(
    const float* __restrict__ vagg, const float* __restrict__ t_in,
    const float* __restrict__ s_in, const float* __restrict__ skip,
    const float* __restrict__ We, float* __restrict__ pooled) {
    __shared__ float tsh[128];
    __shared__ float ssh[8];
    int c = threadIdx.x;  // 128
    float pool_acc = 0.f;
    for (int n = blockIdx.x; n < N_NODES; n += gridDim.x) {
        tsh[c] = t_in[(size_t)n * 128 + c];
        if (c < 8) ssh[c] = s_in[(size_t)n * 8 + c];
        __syncthreads();
        float acc = 0.f;
        #pragma unroll
        for (int h = 0; h < HEADS; ++h) {
            float val = vagg[(size_t)n * HC + h * 128 + c];
            const float* wp = We + h * 128 + c;
            const float* tp = tsh + h * 16;
            float ts = 0.f;
            #pragma unroll
            for (int f = 0; f < 16; ++f) ts += tp[f] * wp[(size_t)f * HC];
            acc += (val + ts) / (ssh[h] + 1e-16f);
        }
        float o = acc * 0.125f + skip[(size_t)n * 128 + c];
        o = fmaxf(o, 0.f);
        pool_acc += o;
        __syncthreads();
    }
    atomAddF(&pooled[c], pool_acc);
}

// ---------------- final: out[0] = pooled @ Wd + bd ----------------
__global__ __launch_bounds__(64) void final_kernel(
    const float* __restrict__ pooled, const float* __restrict__ Wd,
    const float* __restrict__ bd, float* __restrict__ out) {
    int l = threadIdx.x;  // 64
    float vv = pooled[2 * l] * Wd[2 * l] + pooled[2 * l + 1] * Wd[2 * l + 1];
    vv += __shfl_xor(vv, 1);  vv += __shfl_xor(vv, 2);  vv += __shfl_xor(vv, 4);
    vv += __shfl_xor(vv, 8);  vv += __shfl_xor(vv, 16); vv += __shfl_xor(vv, 32);
    if (l == 0) out[0] = vv + bd[0];
}

extern "C" void kernel_launch(void* const* d_in, const int* in_sizes, int n_in,
                              void* d_out, int out_size, void* d_ws, size_t ws_size,
                              hipStream_t stream) {
    const float* x     = (const float*)d_in[0];
    const float* eattr = (const float*)d_in[1];
    const int*   ei    = (const int*)d_in[2];
    const float* Wq    = (const float*)d_in[3];
    const float* bq    = (const float*)d_in[4];
    const float* Wk    = (const float*)d_in[5];
    const float* bk    = (const float*)d_in[6];
    const float* Wv    = (const float*)d_in[7];
    const float* bv    = (const float*)d_in[8];
    const float* We    = (const float*)d_in[9];
    const float* Wskip = (const float*)d_in[10];
    const float* bskip = (const float*)d_in[11];
    const float* Wd    = (const float*)d_in[12];
    const float* bd    = (const float*)d_in[13];
    float* out = (float*)d_out;

    // workspace layout (floats)
    float* ws = (float*)d_ws;
    float* q     = ws;                        // 10,240,000
    float* k     = q + (size_t)N_NODES * HC;  // 10,240,000
    float* v     = k + (size_t)N_NODES * HC;  // 10,240,000
    float* skip  = v + (size_t)N_NODES * HC;  // 1,280,000
    float* qWe   = skip + (size_t)N_NODES * 128;  // 1,280,000
    float* s_acc = qWe + (size_t)N_NODES * 128;   // 80,000      (zeroed)
    float* t_acc = s_acc + (size_t)N_NODES * 8;   // 1,280,000   (zeroed)
    float* vagg  = t_acc + (size_t)N_NODES * 128; // 10,240,000  (zeroed)
    float* pooled = vagg + (size_t)N_NODES * HC;  // 128         (zeroed)

    size_t zero_floats = (size_t)N_NODES * 8 + (size_t)N_NODES * 128 +
                         (size_t)N_NODES * HC + 128;
    hipMemsetAsync(s_acc, 0, zero_floats * sizeof(float), stream);

    dim3 blk(256);
    // q, k, v: [10000,128] @ [128,1024]
    gemm_bias_kernel<<<dim3(HC / GBN, (N_NODES + GBM - 1) / GBM), blk, 0, stream>>>(
        x, Wq, bq, q, N_NODES, HC, F_NODE);
    gemm_bias_kernel<<<dim3(HC / GBN, (N_NODES + GBM - 1) / GBM), blk, 0, stream>>>(
        x, Wk, bk, k, N_NODES, HC, F_NODE);
    gemm_bias_kernel<<<dim3(HC / GBN, (N_NODES + GBM - 1) / GBM), blk, 0, stream>>>(
        x, Wv, bv, v, N_NODES, HC, F_NODE);
    // skip: [10000,128] @ [128,128]
    gemm_bias_kernel<<<dim3(128 / GBN, (N_NODES + GBM - 1) / GBM), blk, 0, stream>>>(
        x, Wskip, bskip, skip, N_NODES, 128, F_NODE);

    qwe_kernel<<<N_NODES, 128, 0, stream>>>(q, We, qWe);

    edge_kernel<<<N_EDGES / 4, 256, 0, stream>>>(q, k, v, qWe, eattr, ei,
                                                 s_acc, t_acc, vagg);

    node_epilogue<<<256, 128, 0, stream>>>(vagg, t_acc, s_acc, skip, We, pooled);

    final_kernel<<<1, 64, 0, stream>>>(pooled, Wd, bd, out);
}

// Round 2
// 507.342 us; speedup vs baseline: 3.5853x; 3.5853x over previous
//
#include <hip/hip_runtime.h>
#include <hip/hip_bf16.h>

#define N_NODES 10000
#define N_EDGES 100000
#define F_NODE 128
#define HEADS 8
#define OUT_CH 128
#define HC 1024

__device__ __forceinline__ void atomAddF(float* p, float v) {
    unsafeAtomicAdd(p, v);   // hardware global_atomic_add_f32
}

// ---------------- GEMM: C[M,N] = A[M,K] @ B[K,N] + bias[N] ----------------
#define GBM 64
#define GBN 64
#define GBK 32
__global__ __launch_bounds__(256) void gemm_bias_kernel(
    const float* __restrict__ A, const float* __restrict__ B,
    const float* __restrict__ bias, float* __restrict__ C,
    int M, int N, int K) {
    __shared__ float As[GBK][GBM + 1];
    __shared__ float Bs[GBK][GBN];
    int tid = threadIdx.x;
    int n0 = blockIdx.x * GBN;
    int m0 = blockIdx.y * GBM;
    int tm = (tid >> 4) * 4;
    int tn = (tid & 15) * 4;
    float acc[4][4] = {};
    for (int k0 = 0; k0 < K; k0 += GBK) {
        #pragma unroll
        for (int t = 0; t < 2; ++t) {
            int f4 = tid + t * 256;
            int r = f4 >> 3;
            int c4 = (f4 & 7) << 2;
            float4 av = make_float4(0.f, 0.f, 0.f, 0.f);
            int gr = m0 + r;
            if (gr < M) av = *(const float4*)(A + (size_t)gr * K + k0 + c4);
            As[c4 + 0][r] = av.x; As[c4 + 1][r] = av.y;
            As[c4 + 2][r] = av.z; As[c4 + 3][r] = av.w;
        }
        #pragma unroll
        for (int t = 0; t < 2; ++t) {
            int f4 = tid + t * 256;
            int r = f4 >> 4;
            int c4 = (f4 & 15) << 2;
            *(float4*)(&Bs[r][c4]) = *(const float4*)(B + (size_t)(k0 + r) * N + n0 + c4);
        }
        __syncthreads();
        #pragma unroll
        for (int kk = 0; kk < GBK; ++kk) {
            float a[4], b[4];
            #pragma unroll
            for (int i = 0; i < 4; ++i) a[i] = As[kk][tm + i];
            #pragma unroll
            for (int j = 0; j < 4; ++j) b[j] = Bs[kk][tn + j];
            #pragma unroll
            for (int i = 0; i < 4; ++i)
                #pragma unroll
                for (int j = 0; j < 4; ++j)
                    acc[i][j] += a[i] * b[j];
        }
        __syncthreads();
    }
    #pragma unroll
    for (int i = 0; i < 4; ++i) {
        int gr = m0 + tm + i;
        if (gr < M) {
            #pragma unroll
            for (int j = 0; j < 4; ++j)
                C[(size_t)gr * N + n0 + tn + j] = acc[i][j] + bias[n0 + tn + j];
        }
    }
}

// ---------------- qWe[n, h*16+f] = sum_c q[n,h*128+c] * We[f*1024 + h*128 + c]
__global__ __launch_bounds__(128) void qwe_kernel(
    const float* __restrict__ q, const float* __restrict__ We,
    float* __restrict__ qWe) {
    __shared__ float qrow[HC];
    int n = blockIdx.x;
    int t = threadIdx.x;
    #pragma unroll
    for (int i = 0; i < 8; ++i) qrow[t + 128 * i] = q[(size_t)n * HC + t + 128 * i];
    __syncthreads();
    int h = t >> 4, f = t & 15;
    const float* wp = We + (size_t)f * HC + h * 128;
    const float* qp = qrow + h * 128;
    float s = 0.f;
    #pragma unroll
    for (int c = 0; c < 128; ++c) s += qp[c] * wp[c];
    qWe[(size_t)n * 128 + t] = s;
}

// ---------------- CSR build ----------------
__global__ __launch_bounds__(256) void count_kernel(const int* __restrict__ ei,
                                                    int* __restrict__ cnt) {
    int e = blockIdx.x * 256 + threadIdx.x;
    if (e < N_EDGES) atomicAdd(&cnt[ei[N_EDGES + e]], 1);
}

__global__ __launch_bounds__(256) void scan_kernel(const int* __restrict__ cnt,
                                                   int* __restrict__ offs,
                                                   int* __restrict__ cursor) {
    __shared__ int sums[256];
    int t = threadIdx.x;
    const int CH = (N_NODES + 255) / 256;  // 40
    int base = t * CH;
    int s = 0;
    for (int i = 0; i < CH; ++i) {
        int idx = base + i;
        if (idx < N_NODES) s += cnt[idx];
    }
    sums[t] = s;
    __syncthreads();
    for (int off = 1; off < 256; off <<= 1) {
        int vprev = (t >= off) ? sums[t - off] : 0;
        __syncthreads();
        sums[t] += vprev;
        __syncthreads();
    }
    int run = (t == 0) ? 0 : sums[t - 1];
    for (int i = 0; i < CH; ++i) {
        int idx = base + i;
        if (idx < N_NODES) {
            offs[idx] = run;
            cursor[idx] = run;
            run += cnt[idx];
        }
    }
    if (t == 255) offs[N_NODES] = run;
}

__global__ __launch_bounds__(256) void scatter_kernel(const int* __restrict__ ei,
                                                      int* __restrict__ cursor,
                                                      int* __restrict__ eidx) {
    int e = blockIdx.x * 256 + threadIdx.x;
    if (e < N_EDGES) {
        int dst = ei[N_EDGES + e];
        int pos = atomicAdd(&cursor[dst], 1);
        eidx[pos] = e;
    }
}

// ---------------- fused node-centric attention + epilogue ----------------
// Block = 256 threads = 8 head-groups of 32 lanes. Thread t owns flat
// channels 4t..4t+3 (head h = t>>5). No atomics in the edge loop.
__global__ __launch_bounds__(256) void node_kernel(
    const float* __restrict__ q, const float* __restrict__ k,
    const float* __restrict__ v, const float* __restrict__ qWe,
    const float* __restrict__ ea, const int* __restrict__ ei,
    const int* __restrict__ eidx, const int* __restrict__ offs,
    const float* __restrict__ skip, const float* __restrict__ We,
    float* __restrict__ pooled) {
    __shared__ float res[1024];
    int t = threadIdx.x;
    int lig = t & 31;          // lane in 32-lane head-group
    int h = t >> 5;            // head
    bool lo16 = (lig < 16);
    const float scale = 0.08838834764831845f;  // 1/sqrt(128)

    float pool_acc = 0.f;
    for (int n = blockIdx.x; n < N_NODES; n += gridDim.x) {
        float4 q4 = *(const float4*)(q + (size_t)n * HC + 4 * t);
        float qwe_r = lo16 ? qWe[(size_t)n * 128 + h * 16 + lig] : 0.f;
        int e0 = offs[n], e1 = offs[n + 1];
        float va0 = 0.f, va1 = 0.f, va2 = 0.f, va3 = 0.f;
        float s_reg = 0.f, t_reg = 0.f;
        for (int ii = e0; ii < e1; ++ii) {
            int e = eidx[ii];
            int src = ei[e];
            float eav = lo16 ? ea[(size_t)e * 16 + lig] : 0.f;
            float4 k4 = *(const float4*)(k + (size_t)src * HC + 4 * t);
            float4 v4 = *(const float4*)(v + (size_t)src * HC + 4 * t);
            // per-head dot(q,k): reduce within 32-lane group
            float d = q4.x * k4.x + q4.y * k4.y + q4.z * k4.z + q4.w * k4.w;
            d += __shfl_xor(d, 1);  d += __shfl_xor(d, 2);  d += __shfl_xor(d, 4);
            d += __shfl_xor(d, 8);  d += __shfl_xor(d, 16);
            // edge term: sum_f ea[f]*qWe[h*16+f] (lanes 0..15 of group)
            float p = eav * qwe_r;
            p += __shfl_xor(p, 1);  p += __shfl_xor(p, 2);
            p += __shfl_xor(p, 4);  p += __shfl_xor(p, 8);
            float et = __shfl(p, 0, 32);
            float a = __expf((d + et) * scale);
            s_reg += a;
            t_reg += a * eav;       // lanes 0..15: t[h,lig]
            va0 += a * v4.x; va1 += a * v4.y; va2 += a * v4.z; va3 += a * v4.w;
        }
        // ts[c] = sum_f t[h,f] * We[f*HC + flat_c]
        float ts0 = 0.f, ts1 = 0.f, ts2 = 0.f, ts3 = 0.f;
        #pragma unroll
        for (int f = 0; f < 16; ++f) {
            float tf = __shfl(t_reg, f, 32);
            const float* wp = We + (size_t)f * HC + 4 * t;
            ts0 += tf * wp[0]; ts1 += tf * wp[1];
            ts2 += tf * wp[2]; ts3 += tf * wp[3];
        }
        float inv = 1.f / (s_reg + 1e-16f);
        res[4 * t + 0] = (va0 + ts0) * inv;
        res[4 * t + 1] = (va1 + ts1) * inv;
        res[4 * t + 2] = (va2 + ts2) * inv;
        res[4 * t + 3] = (va3 + ts3) * inv;
        __syncthreads();
        if (t < 128) {
            float o = 0.f;
            #pragma unroll
            for (int hh = 0; hh < 8; ++hh) o += res[hh * 128 + t];
            o = o * 0.125f + skip[(size_t)n * 128 + t];
            pool_acc += fmaxf(o, 0.f);
        }
        __syncthreads();
    }
    if (t < 128) atomAddF(&pooled[t], pool_acc);
}

// ---------------- final: out[0] = pooled @ Wd + bd ----------------
__global__ __launch_bounds__(64) void final_kernel(
    const float* __restrict__ pooled, const float* __restrict__ Wd,
    const float* __restrict__ bd, float* __restrict__ out) {
    int l = threadIdx.x;
    float vv = pooled[2 * l] * Wd[2 * l] + pooled[2 * l + 1] * Wd[2 * l + 1];
    vv += __shfl_xor(vv, 1);  vv += __shfl_xor(vv, 2);  vv += __shfl_xor(vv, 4);
    vv += __shfl_xor(vv, 8);  vv += __shfl_xor(vv, 16); vv += __shfl_xor(vv, 32);
    if (l == 0) out[0] = vv + bd[0];
}

extern "C" void kernel_launch(void* const* d_in, const int* in_sizes, int n_in,
                              void* d_out, int out_size, void* d_ws, size_t ws_size,
                              hipStream_t stream) {
    const float* x     = (const float*)d_in[0];
    const float* eattr = (const float*)d_in[1];
    const int*   ei    = (const int*)d_in[2];
    const float* Wq    = (const float*)d_in[3];
    const float* bq    = (const float*)d_in[4];
    const float* Wk    = (const float*)d_in[5];
    const float* bk    = (const float*)d_in[6];
    const float* Wv    = (const float*)d_in[7];
    const float* bv    = (const float*)d_in[8];
    const float* We    = (const float*)d_in[9];
    const float* Wskip = (const float*)d_in[10];
    const float* bskip = (const float*)d_in[11];
    const float* Wd    = (const float*)d_in[12];
    const float* bd    = (const float*)d_in[13];
    float* out = (float*)d_out;

    // workspace layout
    float* ws = (float*)d_ws;
    float* q     = ws;                             // 10,240,000 f
    float* k     = q + (size_t)N_NODES * HC;       // 10,240,000 f
    float* v     = k + (size_t)N_NODES * HC;       // 10,240,000 f
    float* skip  = v + (size_t)N_NODES * HC;       // 1,280,000 f
    float* qWe   = skip + (size_t)N_NODES * 128;   // 1,280,000 f
    int*   cnt   = (int*)(qWe + (size_t)N_NODES * 128);  // 10,000 i (zeroed)
    float* pooled = (float*)(cnt + N_NODES);       // 128 f (zeroed)
    int*   offs  = (int*)(pooled + 128);           // 10,001 i
    int*   cursor = offs + N_NODES + 1;            // 10,000 i
    int*   eidx  = cursor + N_NODES;               // 100,000 i

    // zero cnt + pooled in one shot (adjacent)
    hipMemsetAsync(cnt, 0, (N_NODES + 128) * sizeof(int), stream);

    dim3 blk(256);
    gemm_bias_kernel<<<dim3(HC / GBN, (N_NODES + GBM - 1) / GBM), blk, 0, stream>>>(
        x, Wq, bq, q, N_NODES, HC, F_NODE);
    gemm_bias_kernel<<<dim3(HC / GBN, (N_NODES + GBM - 1) / GBM), blk, 0, stream>>>(
        x, Wk, bk, k, N_NODES, HC, F_NODE);
    gemm_bias_kernel<<<dim3(HC / GBN, (N_NODES + GBM - 1) / GBM), blk, 0, stream>>>(
        x, Wv, bv, v, N_NODES, HC, F_NODE);
    gemm_bias_kernel<<<dim3(128 / GBN, (N_NODES + GBM - 1) / GBM), blk, 0, stream>>>(
        x, Wskip, bskip, skip, N_NODES, 128, F_NODE);

    qwe_kernel<<<N_NODES, 128, 0, stream>>>(q, We, qWe);

    count_kernel<<<(N_EDGES + 255) / 256, blk, 0, stream>>>(ei, cnt);
    scan_kernel<<<1, 256, 0, stream>>>(cnt, offs, cursor);
    scatter_kernel<<<(N_EDGES + 255) / 256, blk, 0, stream>>>(ei, cursor, eidx);

    node_kernel<<<2560, 256, 0, stream>>>(q, k, v, qWe, eattr, ei, eidx, offs,
                                          skip, We, pooled);

    final_kernel<<<1, 64, 0, stream>>>(pooled, Wd, bd, out);
}

// Round 3
// 365.652 us; speedup vs baseline: 4.9745x; 1.3875x over previous
//
#include <hip/hip_runtime.h>

#define N_NODES 10000
#define N_EDGES 100000
#define F_NODE 128
#define HEADS 8
#define HC 1024
#define NCOLS 3328   // q(1024) k(1024) v(1024) skip(128) qwe(128)

typedef __attribute__((ext_vector_type(8))) short bf16x8;
typedef __attribute__((ext_vector_type(4))) float f32x4;

__device__ __forceinline__ void atomAddF(float* p, float v) {
    unsafeAtomicAdd(p, v);
}
__device__ __forceinline__ unsigned short f2bf(float f) {
    union { float f; unsigned u; } c; c.f = f;
    unsigned u = c.u + 0x7fffu + ((c.u >> 16) & 1u);  // RNE
    return (unsigned short)(u >> 16);
}
__device__ __forceinline__ float bLo(unsigned x) {
    union { unsigned u; float f; } c; c.u = x << 16; return c.f;
}
__device__ __forceinline__ float bHi(unsigned x) {
    union { unsigned u; float f; } c; c.u = x & 0xffff0000u; return c.f;
}

// ---------------- x -> bf16 ----------------
__global__ __launch_bounds__(256) void conv_x(const float* __restrict__ x,
                                              unsigned short* __restrict__ xb) {
    int i = blockIdx.x * 256 + threadIdx.x;  // float4 index
    if (i < N_NODES * F_NODE / 4) {
        float4 f = ((const float4*)x)[i];
        ushort4 o;
        o.x = f2bf(f.x); o.y = f2bf(f.y); o.z = f2bf(f.z); o.w = f2bf(f.w);
        ((ushort4*)xb)[i] = o;
    }
}

// ---------------- WcatT [3328][128] bf16 (n-major, K fast) ----------------
// cols: [0,1024) Wq | [1024,2048) Wk | [2048,3072) Wv | [3072,3200) Wskip |
// [3200,3328) M where M[d, h*16+f] = sum_c Wq[d,h*128+c]*We[f,h*128+c]
__global__ __launch_bounds__(128) void build_wcat(
    const float* __restrict__ Wq, const float* __restrict__ Wk,
    const float* __restrict__ Wv, const float* __restrict__ Wskip,
    const float* __restrict__ We, unsigned short* __restrict__ wt) {
    __shared__ float wesh[128];
    int n = blockIdx.x, d = threadIdx.x;
    float val;
    if (n < 3072) {
        const float* W = (n < 1024) ? Wq : ((n < 2048) ? Wk : Wv);
        val = W[(size_t)d * HC + (n & 1023)];
    } else if (n < 3200) {
        val = Wskip[(size_t)d * 128 + (n - 3072)];
    } else {
        int hf = n - 3200, h = hf >> 4, f = hf & 15;
        wesh[d] = We[(size_t)f * HC + h * 128 + d];
        __syncthreads();
        const float* wq = Wq + (size_t)d * HC + h * 128;
        float s = 0.f;
        #pragma unroll
        for (int c = 0; c < 128; ++c) s += wq[c] * wesh[c];
        val = s;
    }
    wt[(size_t)n * 128 + d] = f2bf(val);
}

__global__ __launch_bounds__(128) void build_bias(
    const float* __restrict__ bq, const float* __restrict__ bk,
    const float* __restrict__ bv, const float* __restrict__ bskip,
    const float* __restrict__ We, float* __restrict__ bias) {
    int n = blockIdx.x * 128 + threadIdx.x;
    if (n >= NCOLS) return;
    float val;
    if (n < 1024) val = bq[n];
    else if (n < 2048) val = bk[n - 1024];
    else if (n < 3072) val = bv[n - 2048];
    else if (n < 3200) val = bskip[n - 3072];
    else {
        int hf = n - 3200, h = hf >> 4, f = hf & 15;
        float s = 0.f;
        for (int c = 0; c < 128; ++c) s += bq[h * 128 + c] * We[(size_t)f * HC + h * 128 + c];
        val = s;
    }
    bias[n] = val;
}

// ---------------- MFMA GEMM: [10000,128]bf16 x [128,3328]bf16 ----------------
// out: qkv bf16 [10000][3072] (q direct; k,v interleaved per 4ch) ; sq f32 [10000][256]
__global__ __launch_bounds__(256) void gemm_mfma(
    const unsigned short* __restrict__ xb, const unsigned short* __restrict__ wt,
    const float* __restrict__ bias, unsigned short* __restrict__ qkv,
    float* __restrict__ sq) {
    __shared__ unsigned short As[128][72];  // pad 64->72 (row 144 B, 16B-aligned)
    __shared__ unsigned short Bs[128][72];
    int tid = threadIdx.x;
    int n0 = blockIdx.x * 128, m0 = blockIdx.y * 128;
    int w = tid >> 6, lane = tid & 63;
    int wm = (w >> 1) * 64, wn = (w & 1) * 64;
    int quad = lane >> 4, l16 = lane & 15;
    f32x4 acc[4][4];
    #pragma unroll
    for (int i = 0; i < 4; ++i)
        #pragma unroll
        for (int j = 0; j < 4; ++j) acc[i][j] = (f32x4){0.f, 0.f, 0.f, 0.f};

    for (int ko = 0; ko < 128; ko += 64) {
        #pragma unroll
        for (int tI = 0; tI < 4; ++tI) {
            int cId = tid + tI * 256;          // 1024 chunks of 16 B
            int r = cId >> 3, c8 = (cId & 7) << 3;
            int gr = m0 + r;
            uint4 av = make_uint4(0u, 0u, 0u, 0u);
            if (gr < N_NODES)
                av = *(const uint4*)(xb + (size_t)gr * 128 + ko + c8);
            *(uint4*)(&As[r][c8]) = av;
            *(uint4*)(&Bs[r][c8]) =
                *(const uint4*)(wt + (size_t)(n0 + r) * 128 + ko + c8);
        }
        __syncthreads();
        #pragma unroll
        for (int ks = 0; ks < 64; ks += 32) {
            bf16x8 a[4], b[4];
            #pragma unroll
            for (int mt = 0; mt < 4; ++mt)
                a[mt] = *(const bf16x8*)&As[wm + mt * 16 + l16][ks + quad * 8];
            #pragma unroll
            for (int nt = 0; nt < 4; ++nt)
                b[nt] = *(const bf16x8*)&Bs[wn + nt * 16 + l16][ks + quad * 8];
            #pragma unroll
            for (int mt = 0; mt < 4; ++mt)
                #pragma unroll
                for (int nt = 0; nt < 4; ++nt)
                    acc[mt][nt] = __builtin_amdgcn_mfma_f32_16x16x32_bf16(
                        a[mt], b[nt], acc[mt][nt], 0, 0, 0);
        }
        __syncthreads();
    }
    // epilogue: mode per block (n-range aligned to 1024/128)
    int mode = (n0 >= 3072) ? 3 : (n0 >= 2048 ? 2 : (n0 >= 1024 ? 1 : 0));
    #pragma unroll
    for (int mt = 0; mt < 4; ++mt) {
        #pragma unroll
        for (int r = 0; r < 4; ++r) {
            int row = m0 + wm + mt * 16 + quad * 4 + r;
            if (row >= N_NODES) continue;
            #pragma unroll
            for (int nt = 0; nt < 4; ++nt) {
                int col = n0 + wn + nt * 16 + l16;
                float val = acc[mt][nt][r] + bias[col];
                if (mode == 3) {
                    sq[(size_t)row * 256 + (col - 3072)] = val;
                } else {
                    int pos;
                    if (mode == 0) pos = col;
                    else if (mode == 1) { int ch = col - 1024; pos = 1024 + ((ch >> 2) << 3) + (ch & 3); }
                    else { int ch = col - 2048; pos = 1024 + ((ch >> 2) << 3) + 4 + (ch & 3); }
                    qkv[(size_t)row * 3072 + pos] = f2bf(val);
                }
            }
        }
    }
}

// ---------------- CSR build ----------------
__global__ __launch_bounds__(256) void count_kernel(const int* __restrict__ ei,
                                                    int* __restrict__ cnt) {
    int e = blockIdx.x * 256 + threadIdx.x;
    if (e < N_EDGES) atomicAdd(&cnt[ei[N_EDGES + e]], 1);
}

__global__ __launch_bounds__(256) void scan_kernel(const int* __restrict__ cnt,
                                                   int* __restrict__ offs,
                                                   int* __restrict__ cursor) {
    __shared__ int sums[256];
    int t = threadIdx.x;
    const int CH = (N_NODES + 255) / 256;
    int base = t * CH;
    int s = 0;
    for (int i = 0; i < CH; ++i) {
        int idx = base + i;
        if (idx < N_NODES) s += cnt[idx];
    }
    sums[t] = s;
    __syncthreads();
    for (int off = 1; off < 256; off <<= 1) {
        int vprev = (t >= off) ? sums[t - off] : 0;
        __syncthreads();
        sums[t] += vprev;
        __syncthreads();
    }
    int run = (t == 0) ? 0 : sums[t - 1];
    for (int i = 0; i < CH; ++i) {
        int idx = base + i;
        if (idx < N_NODES) {
            offs[idx] = run;
            cursor[idx] = run;
            run += cnt[idx];
        }
    }
    if (t == 255) offs[N_NODES] = run;
}

__global__ __launch_bounds__(256) void scatter_kernel(const int* __restrict__ ei,
                                                      int* __restrict__ cursor,
                                                      int* __restrict__ eidx) {
    int e = blockIdx.x * 256 + threadIdx.x;
    if (e < N_EDGES) {
        int dst = ei[N_EDGES + e];
        int pos = atomicAdd(&cursor[dst], 1);
        eidx[pos] = e;
    }
}

// ---------------- fused node-centric attention + epilogue ----------------
__global__ __launch_bounds__(256) void node_kernel(
    const unsigned short* __restrict__ qkv, const float* __restrict__ sq,
    const float* __restrict__ ea, const int* __restrict__ ei,
    const int* __restrict__ eidx, const int* __restrict__ offs,
    const float* __restrict__ We, float* __restrict__ pooled) {
    __shared__ float res[1024];
    int t = threadIdx.x;
    int lig = t & 31;
    int h = t >> 5;
    bool lo16 = (lig < 16);
    const float scale = 0.08838834764831845f;  // 1/sqrt(128)

    float pool_acc = 0.f;
    for (int n = blockIdx.x; n < N_NODES; n += gridDim.x) {
        uint2 qu = *(const uint2*)(qkv + (size_t)n * 3072 + 4 * t);
        float q0 = bLo(qu.x), q1 = bHi(qu.x), q2 = bLo(qu.y), q3 = bHi(qu.y);
        float qwe_r = lo16 ? sq[(size_t)n * 256 + 128 + h * 16 + lig] : 0.f;
        int e0 = offs[n], e1 = offs[n + 1];
        float va0 = 0.f, va1 = 0.f, va2 = 0.f, va3 = 0.f;
        float s_reg = 0.f, t_reg = 0.f;
        for (int ii = e0; ii < e1; ++ii) {
            int e = eidx[ii];
            int src = ei[e];
            float eav = lo16 ? ea[(size_t)e * 16 + lig] : 0.f;
            uint4 kv = *(const uint4*)(qkv + (size_t)src * 3072 + 1024 + 8 * t);
            float k0 = bLo(kv.x), k1 = bHi(kv.x), k2 = bLo(kv.y), k3 = bHi(kv.y);
            float v0 = bLo(kv.z), v1 = bHi(kv.z), v2 = bLo(kv.w), v3 = bHi(kv.w);
            float d = q0 * k0 + q1 * k1 + q2 * k2 + q3 * k3;
            d += __shfl_xor(d, 1);  d += __shfl_xor(d, 2);  d += __shfl_xor(d, 4);
            d += __shfl_xor(d, 8);  d += __shfl_xor(d, 16);
            float p = eav * qwe_r;
            p += __shfl_xor(p, 1);  p += __shfl_xor(p, 2);
            p += __shfl_xor(p, 4);  p += __shfl_xor(p, 8);
            float et = __shfl(p, 0, 32);
            float a = __expf((d + et) * scale);
            s_reg += a;
            t_reg += a * eav;
            va0 += a * v0; va1 += a * v1; va2 += a * v2; va3 += a * v3;
        }
        float ts0 = 0.f, ts1 = 0.f, ts2 = 0.f, ts3 = 0.f;
        #pragma unroll
        for (int f = 0; f < 16; ++f) {
            float tf = __shfl(t_reg, f, 32);
            const float* wp = We + (size_t)f * HC + 4 * t;
            ts0 += tf * wp[0]; ts1 += tf * wp[1];
            ts2 += tf * wp[2]; ts3 += tf * wp[3];
        }
        float inv = 1.f / (s_reg + 1e-16f);
        res[4 * t + 0] = (va0 + ts0) * inv;
        res[4 * t + 1] = (va1 + ts1) * inv;
        res[4 * t + 2] = (va2 + ts2) * inv;
        res[4 * t + 3] = (va3 + ts3) * inv;
        __syncthreads();
        if (t < 128) {
            float o = 0.f;
            #pragma unroll
            for (int hh = 0; hh < 8; ++hh) o += res[hh * 128 + t];
            o = o * 0.125f + sq[(size_t)n * 256 + t];
            pool_acc += fmaxf(o, 0.f);
        }
        __syncthreads();
    }
    if (t < 128) atomAddF(&pooled[t], pool_acc);
}

// ---------------- final ----------------
__global__ __launch_bounds__(64) void final_kernel(
    const float* __restrict__ pooled, const float* __restrict__ Wd,
    const float* __restrict__ bd, float* __restrict__ out) {
    int l = threadIdx.x;
    float vv = pooled[2 * l] * Wd[2 * l] + pooled[2 * l + 1] * Wd[2 * l + 1];
    vv += __shfl_xor(vv, 1);  vv += __shfl_xor(vv, 2);  vv += __shfl_xor(vv, 4);
    vv += __shfl_xor(vv, 8);  vv += __shfl_xor(vv, 16); vv += __shfl_xor(vv, 32);
    if (l == 0) out[0] = vv + bd[0];
}

extern "C" void kernel_launch(void* const* d_in, const int* in_sizes, int n_in,
                              void* d_out, int out_size, void* d_ws, size_t ws_size,
                              hipStream_t stream) {
    const float* x     = (const float*)d_in[0];
    const float* eattr = (const float*)d_in[1];
    const int*   ei    = (const int*)d_in[2];
    const float* Wq    = (const float*)d_in[3];
    const float* bq    = (const float*)d_in[4];
    const float* Wk    = (const float*)d_in[5];
    const float* bk    = (const float*)d_in[6];
    const float* Wv    = (const float*)d_in[7];
    const float* bv    = (const float*)d_in[8];
    const float* We    = (const float*)d_in[9];
    const float* Wskip = (const float*)d_in[10];
    const float* bskip = (const float*)d_in[11];
    const float* Wd    = (const float*)d_in[12];
    const float* bd    = (const float*)d_in[13];
    float* out = (float*)d_out;

    // workspace layout (bytes, all 16-B aligned)
    char* ws = (char*)d_ws;
    unsigned short* qkv = (unsigned short*)ws;                    // 61,440,000 B
    float* sq   = (float*)(ws + 61440000);                        // 10,240,000 B
    unsigned short* xb = (unsigned short*)(ws + 71680000);        //  2,560,000 B
    unsigned short* wt = (unsigned short*)(ws + 74240000);        //    851,968 B
    float* bias = (float*)(ws + 75091968);                        //     13,312 B
    int* cnt    = (int*)(ws + 75105280);                          //     40,000 B
    float* pooled = (float*)(ws + 75145280);                      //        512 B
    int* offs   = (int*)(ws + 75145792);                          //     40,004 B
    int* cursor = (int*)(ws + 75185796);                          //     40,000 B
    int* eidx   = (int*)(ws + 75225796);                          //    400,000 B

    hipMemsetAsync(cnt, 0, 40000 + 512, stream);  // cnt + pooled adjacent

    conv_x<<<(N_NODES * F_NODE / 4 + 255) / 256, 256, 0, stream>>>(x, xb);
    build_wcat<<<NCOLS, 128, 0, stream>>>(Wq, Wk, Wv, Wskip, We, wt);
    build_bias<<<NCOLS / 128, 128, 0, stream>>>(bq, bk, bv, bskip, We, bias);

    gemm_mfma<<<dim3(NCOLS / 128, (N_NODES + 127) / 128), 256, 0, stream>>>(
        xb, wt, bias, qkv, sq);

    count_kernel<<<(N_EDGES + 255) / 256, 256, 0, stream>>>(ei, cnt);
    scan_kernel<<<1, 256, 0, stream>>>(cnt, offs, cursor);
    scatter_kernel<<<(N_EDGES + 255) / 256, 256, 0, stream>>>(ei, cursor, eidx);

    node_kernel<<<2560, 256, 0, stream>>>(qkv, sq, eattr, ei, eidx, offs, We, pooled);

    final_kernel<<<1, 64, 0, stream>>>(pooled, Wd, bd, out);
}

// Round 4
// 278.601 us; speedup vs baseline: 6.5289x; 1.3125x over previous
//
#include <hip/hip_runtime.h>

#define N_NODES 10000
#define N_EDGES 100000
#define F_NODE 128
#define HEADS 8
#define HC 1024
#define NCOLS 3328   // q(1024) k(1024) v(1024) skip(128) qwe(128)
#define EIDX_CAP 130000  // N_EDGES + 3*N_NODES

typedef __attribute__((ext_vector_type(8))) short bf16x8;
typedef __attribute__((ext_vector_type(4))) float f32x4;

__device__ __forceinline__ void atomAddF(float* p, float v) {
    unsafeAtomicAdd(p, v);
}
__device__ __forceinline__ unsigned short f2bf(float f) {
    union { float f; unsigned u; } c; c.f = f;
    unsigned u = c.u + 0x7fffu + ((c.u >> 16) & 1u);  // RNE
    return (unsigned short)(u >> 16);
}
__device__ __forceinline__ float bLo(unsigned x) {
    union { unsigned u; float f; } c; c.u = x << 16; return c.f;
}
__device__ __forceinline__ float bHi(unsigned x) {
    union { unsigned u; float f; } c; c.u = x & 0xffff0000u; return c.f;
}

// ---------------- x -> bf16 ----------------
__global__ __launch_bounds__(256) void conv_x(const float* __restrict__ x,
                                              unsigned short* __restrict__ xb) {
    int i = blockIdx.x * 256 + threadIdx.x;
    if (i < N_NODES * F_NODE / 4) {
        float4 f = ((const float4*)x)[i];
        ushort4 o;
        o.x = f2bf(f.x); o.y = f2bf(f.y); o.z = f2bf(f.z); o.w = f2bf(f.w);
        ((ushort4*)xb)[i] = o;
    }
}

// ---------------- WcatT [3328][128] bf16 (n-major, K fast) ----------------
__global__ __launch_bounds__(128) void build_wcat(
    const float* __restrict__ Wq, const float* __restrict__ Wk,
    const float* __restrict__ Wv, const float* __restrict__ Wskip,
    const float* __restrict__ We, unsigned short* __restrict__ wt) {
    __shared__ float wesh[128];
    int n = blockIdx.x, d = threadIdx.x;
    float val;
    if (n < 3072) {
        const float* W = (n < 1024) ? Wq : ((n < 2048) ? Wk : Wv);
        val = W[(size_t)d * HC + (n & 1023)];
    } else if (n < 3200) {
        val = Wskip[(size_t)d * 128 + (n - 3072)];
    } else {
        int hf = n - 3200, h = hf >> 4, f = hf & 15;
        wesh[d] = We[(size_t)f * HC + h * 128 + d];
        __syncthreads();
        const float* wq = Wq + (size_t)d * HC + h * 128;
        float s = 0.f;
        #pragma unroll
        for (int c = 0; c < 128; ++c) s += wq[c] * wesh[c];
        val = s;
    }
    wt[(size_t)n * 128 + d] = f2bf(val);
}

__global__ __launch_bounds__(128) void build_bias(
    const float* __restrict__ bq, const float* __restrict__ bk,
    const float* __restrict__ bv, const float* __restrict__ bskip,
    const float* __restrict__ We, float* __restrict__ bias) {
    int n = blockIdx.x * 128 + threadIdx.x;
    if (n >= NCOLS) return;
    float val;
    if (n < 1024) val = bq[n];
    else if (n < 2048) val = bk[n - 1024];
    else if (n < 3072) val = bv[n - 2048];
    else if (n < 3200) val = bskip[n - 3072];
    else {
        int hf = n - 3200, h = hf >> 4, f = hf & 15;
        float s = 0.f;
        for (int c = 0; c < 128; ++c) s += bq[h * 128 + c] * We[(size_t)f * HC + h * 128 + c];
        val = s;
    }
    bias[n] = val;
}

// ---------------- MFMA GEMM: [10000,128]bf16 x [128,3328]bf16 ----------------
// q/k/v -> separate contiguous bf16 [10000][1024]; skip+qwe -> sq f32 [10000][256]
__global__ __launch_bounds__(256) void gemm_mfma(
    const unsigned short* __restrict__ xb, const unsigned short* __restrict__ wt,
    const float* __restrict__ bias, unsigned short* __restrict__ qb,
    unsigned short* __restrict__ kb, unsigned short* __restrict__ vb,
    float* __restrict__ sq) {
    __shared__ unsigned short lds[18432];  // As(9216) + Bs(9216); reused as stage
    unsigned short (*As)[72] = (unsigned short(*)[72])lds;
    unsigned short (*Bs)[72] = (unsigned short(*)[72])(lds + 9216);
    int tid = threadIdx.x;
    int n0 = blockIdx.x * 128, m0 = blockIdx.y * 128;
    int w = tid >> 6, lane = tid & 63;
    int wm = (w >> 1) * 64, wn = (w & 1) * 64;
    int quad = lane >> 4, l16 = lane & 15;
    f32x4 acc[4][4];
    #pragma unroll
    for (int i = 0; i < 4; ++i)
        #pragma unroll
        for (int j = 0; j < 4; ++j) acc[i][j] = (f32x4){0.f, 0.f, 0.f, 0.f};

    for (int ko = 0; ko < 128; ko += 64) {
        #pragma unroll
        for (int tI = 0; tI < 4; ++tI) {
            int cId = tid + tI * 256;
            int r = cId >> 3, c8 = (cId & 7) << 3;
            int gr = m0 + r;
            uint4 av = make_uint4(0u, 0u, 0u, 0u);
            if (gr < N_NODES)
                av = *(const uint4*)(xb + (size_t)gr * 128 + ko + c8);
            *(uint4*)(&As[r][c8]) = av;
            *(uint4*)(&Bs[r][c8]) =
                *(const uint4*)(wt + (size_t)(n0 + r) * 128 + ko + c8);
        }
        __syncthreads();
        #pragma unroll
        for (int ks = 0; ks < 64; ks += 32) {
            bf16x8 a[4], b[4];
            #pragma unroll
            for (int mt = 0; mt < 4; ++mt)
                a[mt] = *(const bf16x8*)&As[wm + mt * 16 + l16][ks + quad * 8];
            #pragma unroll
            for (int nt = 0; nt < 4; ++nt)
                b[nt] = *(const bf16x8*)&Bs[wn + nt * 16 + l16][ks + quad * 8];
            #pragma unroll
            for (int mt = 0; mt < 4; ++mt)
                #pragma unroll
                for (int nt = 0; nt < 4; ++nt)
                    acc[mt][nt] = __builtin_amdgcn_mfma_f32_16x16x32_bf16(
                        a[mt], b[nt], acc[mt][nt], 0, 0, 0);
        }
        __syncthreads();
    }
    int mode = n0 >> 10;  // 0=q 1=k 2=v 3=sq
    if (mode == 3) {
        #pragma unroll
        for (int mt = 0; mt < 4; ++mt)
            #pragma unroll
            for (int r = 0; r < 4; ++r) {
                int row = m0 + wm + mt * 16 + quad * 4 + r;
                if (row >= N_NODES) continue;
                #pragma unroll
                for (int nt = 0; nt < 4; ++nt) {
                    int col = n0 + wn + nt * 16 + l16;
                    sq[(size_t)row * 256 + (col - 3072)] = acc[mt][nt][r] + bias[col];
                }
            }
    } else {
        // stage wave's 64x64 bf16 tile in LDS (reuse; all reads done after barrier)
        unsigned short* wst = lds + w * 4096;
        #pragma unroll
        for (int mt = 0; mt < 4; ++mt)
            #pragma unroll
            for (int r = 0; r < 4; ++r) {
                int rl = mt * 16 + quad * 4 + r;
                #pragma unroll
                for (int nt = 0; nt < 4; ++nt) {
                    int cl = nt * 16 + l16;
                    wst[rl * 64 + cl] = f2bf(acc[mt][nt][r] + bias[n0 + wn + cl]);
                }
            }
        unsigned short* dst = (mode == 0) ? qb : ((mode == 1) ? kb : vb);
        int colbase = (n0 - (mode << 10)) + wn;
        #pragma unroll
        for (int p = 0; p < 8; ++p) {
            int rl = p * 8 + (lane >> 3);
            int row = m0 + wm + rl;
            if (row < N_NODES) {
                uint4 valp = *(const uint4*)(wst + rl * 64 + (lane & 7) * 8);
                *(uint4*)(dst + (size_t)row * 1024 + colbase + (lane & 7) * 8) = valp;
            }
        }
    }
}

// ---------------- CSR build (padded to multiples of 4) ----------------
__global__ __launch_bounds__(256) void count_kernel(const int* __restrict__ ei,
                                                    int* __restrict__ cnt) {
    int e = blockIdx.x * 256 + threadIdx.x;
    if (e < N_EDGES) atomicAdd(&cnt[ei[N_EDGES + e]], 1);
}

__global__ __launch_bounds__(256) void fill_kernel(int2* __restrict__ eidx2) {
    int i = blockIdx.x * 256 + threadIdx.x;
    if (i < EIDX_CAP) eidx2[i] = make_int2(0, -1);
}

__global__ __launch_bounds__(256) void scan_kernel(const int* __restrict__ cnt,
                                                   int* __restrict__ offs,
                                                   int* __restrict__ cursor) {
    __shared__ int sums[256];
    int t = threadIdx.x;
    const int CH = (N_NODES + 255) / 256;
    int base = t * CH;
    int s = 0;
    for (int i = 0; i < CH; ++i) {
        int idx = base + i;
        if (idx < N_NODES) s += (cnt[idx] + 3) & ~3;
    }
    sums[t] = s;
    __syncthreads();
    for (int off = 1; off < 256; off <<= 1) {
        int vprev = (t >= off) ? sums[t - off] : 0;
        __syncthreads();
        sums[t] += vprev;
        __syncthreads();
    }
    int run = (t == 0) ? 0 : sums[t - 1];
    for (int i = 0; i < CH; ++i) {
        int idx = base + i;
        if (idx < N_NODES) {
            offs[idx] = run;
            cursor[idx] = run;
            run += (cnt[idx] + 3) & ~3;
        }
    }
    if (t == 255) offs[N_NODES] = run;
}

__global__ __launch_bounds__(256) void scatter_kernel(const int* __restrict__ ei,
                                                      int* __restrict__ cursor,
                                                      int2* __restrict__ eidx2) {
    int e = blockIdx.x * 256 + threadIdx.x;
    if (e < N_EDGES) {
        int src = ei[e];
        int dst = ei[N_EDGES + e];
        int pos = atomicAdd(&cursor[dst], 1);
        eidx2[pos] = make_int2(src, e);
    }
}

// ---------------- fused node-centric attention + epilogue ----------------
__global__ __launch_bounds__(256) void node_kernel(
    const unsigned short* __restrict__ qb, const unsigned short* __restrict__ kb,
    const unsigned short* __restrict__ vb, const float* __restrict__ sq,
    const float* __restrict__ ea, const int2* __restrict__ eidx2,
    const int* __restrict__ offs, const float* __restrict__ We,
    float* __restrict__ pooled) {
    __shared__ float res[1024];
    int t = threadIdx.x;
    int lig = t & 31;
    int h = t >> 5;
    bool lo16 = (lig < 16);
    const float scale = 0.08838834764831845f;  // 1/sqrt(128)

    float pool_acc = 0.f;
    for (int n = blockIdx.x; n < N_NODES; n += gridDim.x) {
        uint2 qu = *(const uint2*)(qb + (size_t)n * 1024 + 4 * t);
        float q0 = bLo(qu.x), q1 = bHi(qu.x), q2 = bLo(qu.y), q3 = bHi(qu.y);
        float qwe_r = lo16 ? sq[(size_t)n * 256 + 128 + h * 16 + lig] : 0.f;
        int e0 = offs[n], e1 = offs[n + 1];  // padded to multiple of 4
        float va0 = 0.f, va1 = 0.f, va2 = 0.f, va3 = 0.f;
        float s_reg = 0.f, t_reg = 0.f;
        for (int ii = e0; ii < e1; ii += 4) {
            int2 se[4];
            #pragma unroll
            for (int j = 0; j < 4; ++j) se[j] = eidx2[ii + j];
            uint2 kk[4], vv[4];
            float eav[4];
            #pragma unroll
            for (int j = 0; j < 4; ++j) {
                int src = se[j].x;
                kk[j] = *(const uint2*)(kb + (size_t)src * 1024 + 4 * t);
                vv[j] = *(const uint2*)(vb + (size_t)src * 1024 + 4 * t);
                int ee = (se[j].y < 0) ? 0 : se[j].y;
                eav[j] = lo16 ? ea[(size_t)ee * 16 + lig] : 0.f;
            }
            #pragma unroll
            for (int j = 0; j < 4; ++j) {
                float k0 = bLo(kk[j].x), k1 = bHi(kk[j].x);
                float k2 = bLo(kk[j].y), k3 = bHi(kk[j].y);
                float d = q0 * k0 + q1 * k1 + q2 * k2 + q3 * k3;
                d += __shfl_xor(d, 1);  d += __shfl_xor(d, 2);  d += __shfl_xor(d, 4);
                d += __shfl_xor(d, 8);  d += __shfl_xor(d, 16);
                float p = eav[j] * qwe_r;
                p += __shfl_xor(p, 1);  p += __shfl_xor(p, 2);
                p += __shfl_xor(p, 4);  p += __shfl_xor(p, 8);
                float et = __shfl(p, 0, 32);
                float a = __expf((d + et) * scale);
                a = (se[j].y < 0) ? 0.f : a;
                s_reg += a;
                t_reg += a * eav[j];
                va0 += a * bLo(vv[j].x); va1 += a * bHi(vv[j].x);
                va2 += a * bLo(vv[j].y); va3 += a * bHi(vv[j].y);
            }
        }
        float ts0 = 0.f, ts1 = 0.f, ts2 = 0.f, ts3 = 0.f;
        #pragma unroll
        for (int f = 0; f < 16; ++f) {
            float tf = __shfl(t_reg, f, 32);
            const float* wp = We + (size_t)f * HC + 4 * t;
            ts0 += tf * wp[0]; ts1 += tf * wp[1];
            ts2 += tf * wp[2]; ts3 += tf * wp[3];
        }
        float inv = 1.f / (s_reg + 1e-16f);
        res[4 * t + 0] = (va0 + ts0) * inv;
        res[4 * t + 1] = (va1 + ts1) * inv;
        res[4 * t + 2] = (va2 + ts2) * inv;
        res[4 * t + 3] = (va3 + ts3) * inv;
        __syncthreads();
        if (t < 128) {
            float o = 0.f;
            #pragma unroll
            for (int hh = 0; hh < 8; ++hh) o += res[hh * 128 + t];
            o = o * 0.125f + sq[(size_t)n * 256 + t];
            pool_acc += fmaxf(o, 0.f);
        }
        __syncthreads();
    }
    if (t < 128) atomAddF(&pooled[t], pool_acc);
}

// ---------------- final ----------------
__global__ __launch_bounds__(64) void final_kernel(
    const float* __restrict__ pooled, const float* __restrict__ Wd,
    const float* __restrict__ bd, float* __restrict__ out) {
    int l = threadIdx.x;
    float vv = pooled[2 * l] * Wd[2 * l] + pooled[2 * l + 1] * Wd[2 * l + 1];
    vv += __shfl_xor(vv, 1);  vv += __shfl_xor(vv, 2);  vv += __shfl_xor(vv, 4);
    vv += __shfl_xor(vv, 8);  vv += __shfl_xor(vv, 16); vv += __shfl_xor(vv, 32);
    if (l == 0) out[0] = vv + bd[0];
}

extern "C" void kernel_launch(void* const* d_in, const int* in_sizes, int n_in,
                              void* d_out, int out_size, void* d_ws, size_t ws_size,
                              hipStream_t stream) {
    const float* x     = (const float*)d_in[0];
    const float* eattr = (const float*)d_in[1];
    const int*   ei    = (const int*)d_in[2];
    const float* Wq    = (const float*)d_in[3];
    const float* bq    = (const float*)d_in[4];
    const float* Wk    = (const float*)d_in[5];
    const float* bk    = (const float*)d_in[6];
    const float* Wv    = (const float*)d_in[7];
    const float* bv    = (const float*)d_in[8];
    const float* We    = (const float*)d_in[9];
    const float* Wskip = (const float*)d_in[10];
    const float* bskip = (const float*)d_in[11];
    const float* Wd    = (const float*)d_in[12];
    const float* bd    = (const float*)d_in[13];
    float* out = (float*)d_out;

    // workspace layout (byte offsets, 16B-aligned where needed)
    char* ws = (char*)d_ws;
    unsigned short* qb = (unsigned short*)(ws + 0);            // 20,480,000
    unsigned short* kb = (unsigned short*)(ws + 20480000);     // 20,480,000
    unsigned short* vb = (unsigned short*)(ws + 40960000);     // 20,480,000
    float* sq   = (float*)(ws + 61440000);                     // 10,240,000
    unsigned short* xb = (unsigned short*)(ws + 71680000);     //  2,560,000
    unsigned short* wt = (unsigned short*)(ws + 74240000);     //    851,968
    float* bias = (float*)(ws + 75091968);                     //     13,312
    int* cnt    = (int*)(ws + 75105280);                       //     40,000
    float* pooled = (float*)(ws + 75145280);                   //        512
    int* offs   = (int*)(ws + 75145792);                       //     40,004
    int* cursor = (int*)(ws + 75185796);                       //     40,000
    int2* eidx2 = (int2*)(ws + 75225800);                      //  1,040,000

    hipMemsetAsync(cnt, 0, 40000 + 512, stream);  // cnt + pooled adjacent

    conv_x<<<(N_NODES * F_NODE / 4 + 255) / 256, 256, 0, stream>>>(x, xb);
    build_wcat<<<NCOLS, 128, 0, stream>>>(Wq, Wk, Wv, Wskip, We, wt);
    build_bias<<<NCOLS / 128, 128, 0, stream>>>(bq, bk, bv, bskip, We, bias);

    gemm_mfma<<<dim3(NCOLS / 128, (N_NODES + 127) / 128), 256, 0, stream>>>(
        xb, wt, bias, qb, kb, vb, sq);

    count_kernel<<<(N_EDGES + 255) / 256, 256, 0, stream>>>(ei, cnt);
    fill_kernel<<<(EIDX_CAP + 255) / 256, 256, 0, stream>>>(eidx2);
    scan_kernel<<<1, 256, 0, stream>>>(cnt, offs, cursor);
    scatter_kernel<<<(N_EDGES + 255) / 256, 256, 0, stream>>>(ei, cursor, eidx2);

    node_kernel<<<2560, 256, 0, stream>>>(qb, kb, vb, sq, eattr, eidx2, offs,
                                          We, pooled);

    final_kernel<<<1, 64, 0, stream>>>(pooled, Wd, bd, out);
}